// Round 14
// baseline (105.740 us; speedup 1.0000x reference)
//
#include <hip/hip_runtime.h>
#include <hip/hip_bf16.h>

// CustomAttention: proj = tanh(H @ W^T + b); scores = proj @ c; attn = softmax_L(scores);
// out0 = sum_l H * attn ; out1 = attn.   B=64, L=512, D=768.  M = B*L = 32768.
// Round 14: r13 (no convert_h; GEMM reads fp32 H via global_load_lds; wsum reads
// fp32 H) with the A-LDS layout rebuilt as TWO packed-pair buffers (LO = k%8<4,
// HI = k%8>=4) whose read-slot algebra is byte-identical to the r10/r12 f16
// pattern that measured 0 bank conflicts: byte = lr*128 + ((half*4+q)^(m&7))*16.

using half8 = __attribute__((ext_vector_type(8))) _Float16;   // MFMA A/B frag (4 VGPRs)
using f32x4 = __attribute__((ext_vector_type(4))) float;      // MFMA C/D frag

#define AS1 __attribute__((address_space(1)))
#define AS3 __attribute__((address_space(3)))

__device__ __forceinline__ void gload_lds16(const void* g, void* l) {
  __builtin_amdgcn_global_load_lds((const AS1 void*)g, (AS3 void*)l, 16, 0, 0);
}

__device__ __forceinline__ unsigned short f2h(float x) {
  _Float16 h = (_Float16)x;                       // v_cvt_f16_f32, RNE
  return __builtin_bit_cast(unsigned short, h);
}

// tanh(x) = 1 - 2/(exp(2x)+1).
__device__ __forceinline__ float tanh_fast(float x) {
  return 1.0f - __fdividef(2.0f, 1.0f + __expf(2.0f * x));
}

// ---------------- W conversion (1.18 MB, ~0.5 us) ----------------
__global__ void convert_w(const float4* __restrict__ W4, ushort4* __restrict__ Wt) {
  int i = blockIdx.x * 256 + threadIdx.x;   // 147456 quads
  float4 x = W4[i];
  ushort4 o;
  o.x = f2h(x.x); o.y = f2h(x.y); o.z = f2h(x.z); o.w = f2h(x.w);
  Wt[i] = o;
}

// ---------------- GEMM (128x128, BK=32, fp32 A in LO/HI buffers) -------------
// A LDS (per slot): two 8-KB buffers.  Logical tile row r in [0,128), k in
// [0,32): half = r>>6, lr = r&63, v = k>>3, j = k&7.  LO holds j<4, HI j>=4:
//   bufX byte = lr*128 + ((half*4 + v)^(lr&7))*16 + (j&3)*4.
// Read (lane m,q; frag mi): lr = mi*16+m, slot = ((half*4+q)^(m&7))*16 -- the
// EXACT slot algebra of the r10/r12 f16 layout (measured 0 conflicts).
// Staging: gload_lds linear dst; inverse source: thread t, chunk c ->
//   au = (t&7)^((t>>3)&7); row = (au>>2)*64 + c*32 + (t>>3);
//   LO byte = row*3072 + kt*128 + (au&3)*32 ; HI = +16.
// B: f16 packed-pair layout + staging identical to r10/r12/r13 (measured 0).
// Grid: flat 1536; XCD decode (bid&7) keeps the 6 same-mtile blocks on one XCD.
__global__ __launch_bounds__(256) void gemm_scores(
    const float* __restrict__ H, const ushort* __restrict__ Wt,
    const float* __restrict__ bias, const float* __restrict__ cvec,
    float* __restrict__ part) {
  __shared__ float  ldsAlo[2][2048];  // 2 x 8 KB
  __shared__ float  ldsAhi[2][2048];  // 2 x 8 KB
  __shared__ ushort ldsB[2][4096];    // 2 x 8 KB
  __shared__ float scpart[2][128];    // 1 KB   (total 50176 B -> 3 blocks/CU)

  const int tid = threadIdx.x;
  const int lane = tid & 63;
  const int wid = tid >> 6;           // 0..3
  const int wr = wid >> 1, wc = wid & 1;
  const int m = lane & 15, q = lane >> 4;

  const int bid = blockIdx.x;         // 0..1535
  const int xcd = bid & 7;
  const int slot = bid >> 3;          // 0..191
  const int mtile = xcd * 32 + slot / 6;
  const int ntile = slot % 6;

  const char* const Abase = (const char*)(H + (size_t)(mtile * 128) * 768);
  const char* const Bbase = (const char*)Wt + (size_t)(ntile * 128) * 1536;

  // --- A staging source inverse (LO/HI): thread t, chunk c in {0,1} ---
  const int tr3 = tid >> 3;                       // 0..31
  const int au = (tid & 7) ^ (tr3 & 7);           // u' = half*4 + v
  const size_t asrcLO = (size_t)((au >> 2) * 64 + tr3) * 3072 + (au & 3) * 32;
  // chunk c adds c*32 rows = c*98304 B; kt adds kt*128 B; HI adds +16.

  // --- B staging source (f16 packed-pair, as r10/r12/r13) ---
  const int up = au;                               // same formula
  const size_t bsrc0 = (size_t)((up >> 2) * 64 + tr3) * 1536 + (up & 3) * 16;
  const size_t bsrc1 = (size_t)((up >> 2) * 64 + 32 + tr3) * 1536 + (up & 3) * 16;
  const int wavebase = wid << 10;

  f32x4 acc[4][4];
  #pragma unroll
  for (int i = 0; i < 4; ++i)
    #pragma unroll
    for (int j = 0; j < 4; ++j)
      acc[i][j] = (f32x4){0.f, 0.f, 0.f, 0.f};

  auto stage = [&](int kt, int s) {
    #pragma unroll
    for (int c = 0; c < 2; ++c) {
      const char* srcLO = Abase + asrcLO + (size_t)c * 98304 + kt * 128;
      gload_lds16(srcLO,      (char*)ldsAlo[s] + c * 4096 + wavebase);
      gload_lds16(srcLO + 16, (char*)ldsAhi[s] + c * 4096 + wavebase);
    }
    gload_lds16(Bbase + bsrc0 + kt * 64, (char*)ldsB[s] + wavebase);
    gload_lds16(Bbase + bsrc1 + kt * 64, (char*)ldsB[s] + 4096 + wavebase);
  };

  // read-side swizzled byte offsets (r10's exact measured-0 algebra)
  const int aslot = ((wr * 4 + q) ^ (m & 7)) * 16;  // A: half = wr
  const int bslot = ((wc * 4 + q) ^ (m & 7)) * 16;  // B (r10-identical)

  auto compute = [&](int s) {
    const char* AbLO = (const char*)ldsAlo[s];
    const char* AbHI = (const char*)ldsAhi[s];
    const char* Bb = (const char*)ldsB[s];
    half8 areg[4], breg[4];
    #pragma unroll
    for (int mi = 0; mi < 4; ++mi) {
      int rowb = (mi * 16 + m) * 128;               // lr*128 (lr = mi*16+m)
      f32x4 lo = *(const f32x4*)(AbLO + rowb + aslot);   // k = 8q..8q+3
      f32x4 hi = *(const f32x4*)(AbHI + rowb + aslot);   // k = 8q+4..8q+7
      half8 r;
      r[0] = (_Float16)lo[0]; r[1] = (_Float16)lo[1];
      r[2] = (_Float16)lo[2]; r[3] = (_Float16)lo[3];
      r[4] = (_Float16)hi[0]; r[5] = (_Float16)hi[1];
      r[6] = (_Float16)hi[2]; r[7] = (_Float16)hi[3];
      areg[mi] = r;
    }
    #pragma unroll
    for (int ni = 0; ni < 4; ++ni)
      breg[ni] = *(const half8*)(Bb + (ni * 16 + m) * 128 + bslot);
    __builtin_amdgcn_s_setprio(1);
    #pragma unroll
    for (int mi = 0; mi < 4; ++mi)
      #pragma unroll
      for (int ni = 0; ni < 4; ++ni)
        acc[mi][ni] = __builtin_amdgcn_mfma_f32_16x16x32_f16(
            areg[mi], breg[ni], acc[mi][ni], 0, 0, 0);
    __builtin_amdgcn_s_setprio(0);
  };

  // --- dbuf loop: stage(t+1) | compute(t) | sync  (r4-proven) ---
  // NOTE: A wave-tile is rows wr*64..wr*64+63 -> half = wr, lr = mi*16+m.
  stage(0, 0);
  __syncthreads();
  #pragma unroll
  for (int t = 0; t < 24; ++t) {
    if (t < 23) stage(t + 1, (t + 1) & 1);
    compute(t & 1);
    __syncthreads();
  }

  // epilogue: score partial = sum_e tanh(acc + b[e]) * c[e]
  float bb[4], cc[4];
  #pragma unroll
  for (int ni = 0; ni < 4; ++ni) {
    int e = ntile * 128 + wc * 64 + ni * 16 + m;
    bb[ni] = bias[e];
    cc[ni] = cvec[e];
  }
  #pragma unroll
  for (int mi = 0; mi < 4; ++mi) {
    #pragma unroll
    for (int j = 0; j < 4; ++j) {
      float s = 0.f;
      #pragma unroll
      for (int ni = 0; ni < 4; ++ni)
        s += tanh_fast(acc[mi][ni][j] + bb[ni]) * cc[ni];
      s += __shfl_xor(s, 1);
      s += __shfl_xor(s, 2);
      s += __shfl_xor(s, 4);
      s += __shfl_xor(s, 8);
      if (m == 0) scpart[wc][wr * 64 + mi * 16 + q * 4 + j] = s;
    }
  }
  __syncthreads();
  if (tid < 128)
    part[ntile * 32768 + mtile * 128 + tid] = scpart[0][tid] + scpart[1][tid];
}

// A wave-tile row note: compute() uses lr = mi*16+m with half = wr baked into
// aslot -- logical rows wr*64 + mi*16 + m, matching the C-write (wr*64 offset).

// ---------------- fused softmax + weighted sum (fp32 H, exact) ----------------
__global__ void wsum_fused(const float* __restrict__ H, const float* __restrict__ prt,
                           float* __restrict__ out) {
  int b = blockIdx.x, dc = blockIdx.y;   // grid (64,3), 128 threads
  int t = threadIdx.x;
  __shared__ float w[512];
  __shared__ float redm[2], reds[2];

  float s[4];
  #pragma unroll
  for (int i = 0; i < 4; ++i) {
    int r = b * 512 + t + i * 128;
    s[i] = prt[r] + prt[32768 + r] + prt[2 * 32768 + r] +
           prt[3 * 32768 + r] + prt[4 * 32768 + r] + prt[5 * 32768 + r];
  }
  float mx = fmaxf(fmaxf(s[0], s[1]), fmaxf(s[2], s[3]));
  #pragma unroll
  for (int o = 32; o >= 1; o >>= 1) mx = fmaxf(mx, __shfl_xor(mx, o));
  if ((t & 63) == 0) redm[t >> 6] = mx;
  __syncthreads();
  mx = fmaxf(redm[0], redm[1]);

  float e[4], sm = 0.f;
  #pragma unroll
  for (int i = 0; i < 4; ++i) { e[i] = __expf(s[i] - mx); sm += e[i]; }
  #pragma unroll
  for (int o = 32; o >= 1; o >>= 1) sm += __shfl_xor(sm, o);
  if ((t & 63) == 0) reds[t >> 6] = sm;
  __syncthreads();
  float inv = 1.0f / (reds[0] + reds[1]);
  #pragma unroll
  for (int i = 0; i < 4; ++i) w[t + i * 128] = e[i] * inv;
  __syncthreads();

  int d0 = dc * 256 + t * 2;
  const float2* hp = (const float2*)(H + (size_t)b * 512 * 768 + d0);
  float a0 = 0.f, a1 = 0.f;
  #pragma unroll 8
  for (int l = 0; l < 512; ++l) {
    float2 u = hp[(size_t)l * 384];
    float wl = w[l];
    a0 += wl * u.x;
    a1 += wl * u.y;
  }
  out[b * 768 + d0] = a0;
  out[b * 768 + d0 + 1] = a1;

  if (dc == 0) {
    #pragma unroll
    for (int i = 0; i < 4; ++i)
      out[49152 + b * 512 + t + i * 128] = w[t + i * 128];
  }
}

// ---------------- launch ----------------
extern "C" void kernel_launch(void* const* d_in, const int* in_sizes, int n_in,
                              void* d_out, int out_size, void* d_ws, size_t ws_size,
                              hipStream_t stream) {
  const float* H    = (const float*)d_in[0];   // [64,512,768] fp32
  const float* W    = (const float*)d_in[1];   // [768,768]
  const float* bias = (const float*)d_in[2];   // [768]
  const float* cvec = (const float*)d_in[3];   // [768,1]
  float* out = (float*)d_out;                  // [0,49152): weighted ; [49152,81920): attn

  char* ws = (char*)d_ws;
  ushort* Wt = (ushort*)(ws + 0);              // 1,179,648 B
  float*  prt = (float*)(ws + 1179648);        //   786,432 B ([6][32768])

  hipLaunchKernelGGL(convert_w, dim3(576), dim3(256), 0, stream,
                     (const float4*)W, (ushort4*)Wt);
  hipLaunchKernelGGL(gemm_scores, dim3(1536), dim3(256), 0, stream,
                     H, Wt, bias, cvec, prt);
  hipLaunchKernelGGL(wsum_fused, dim3(64, 3), dim3(128), 0, stream,
                     H, prt, out);
}

// Round 15
// 105.544 us; speedup vs baseline: 1.0019x; 1.0019x over previous
//
#include <hip/hip_runtime.h>
#include <hip/hip_bf16.h>

// CustomAttention: proj = tanh(H @ W^T + b); scores = proj @ c; attn = softmax_L(scores);
// out0 = sum_l H * attn ; out1 = attn.   B=64, L=512, D=768.  M = B*L = 32768.
// Round 15: r14 GEMM (fp32-A direct, 0 conflicts) + free f16 side-product:
// the GEMM stores its in-register f16 A-fragments to a global Ah buffer
// (each of the 6 same-mtile blocks stores steps t%6==ntile, wc==0 waves only
// -> every (row,k) written exactly once, 50 MB spread over a non-BW-bound
// kernel).  wsum then reads f16 Ah (50 MB) instead of fp32 H (100 MB).

using half8 = __attribute__((ext_vector_type(8))) _Float16;   // MFMA A/B frag (4 VGPRs)
using f32x4 = __attribute__((ext_vector_type(4))) float;      // MFMA C/D frag

#define AS1 __attribute__((address_space(1)))
#define AS3 __attribute__((address_space(3)))

__device__ __forceinline__ void gload_lds16(const void* g, void* l) {
  __builtin_amdgcn_global_load_lds((const AS1 void*)g, (AS3 void*)l, 16, 0, 0);
}

__device__ __forceinline__ unsigned short f2h(float x) {
  _Float16 h = (_Float16)x;                       // v_cvt_f16_f32, RNE
  return __builtin_bit_cast(unsigned short, h);
}

// tanh(x) = 1 - 2/(exp(2x)+1).
__device__ __forceinline__ float tanh_fast(float x) {
  return 1.0f - __fdividef(2.0f, 1.0f + __expf(2.0f * x));
}

// ---------------- W conversion (1.18 MB, ~0.5 us) ----------------
__global__ void convert_w(const float4* __restrict__ W4, ushort4* __restrict__ Wt) {
  int i = blockIdx.x * 256 + threadIdx.x;   // 147456 quads
  float4 x = W4[i];
  ushort4 o;
  o.x = f2h(x.x); o.y = f2h(x.y); o.z = f2h(x.z); o.w = f2h(x.w);
  Wt[i] = o;
}

// ---------------- GEMM (128x128, BK=32, fp32 A -> f16 side-product) ----------
// A LDS (per slot): two 8-KB packed-pair buffers (LO = k%8<4, HI = k%8>=4),
// read-slot algebra byte-identical to the r10/r12 f16 pattern (measured 0):
//   byte = lr*128 + ((half*4+q)^(m&7))*16   (half = wr, lr = mi*16+m).
// Staging: gload_lds linear dst; inverse-mapped global source (both-sides).
// B: f16 packed-pair layout + staging identical to r10-r14 (measured 0).
// Side-product: on steps t%6==ntile, wc==0 waves store areg (f16) to Ah:
//   row = mtile*128 + wr*64 + mi*16 + m, cols kt*32 + q*8 .. +7  (16-B store).
// Grid: flat 1536; XCD decode (bid&7) keeps the 6 same-mtile blocks on one XCD.
__global__ __launch_bounds__(256) void gemm_scores(
    const float* __restrict__ H, const ushort* __restrict__ Wt,
    const float* __restrict__ bias, const float* __restrict__ cvec,
    float* __restrict__ part, ushort* __restrict__ Ah) {
  __shared__ float  ldsAlo[2][2048];  // 2 x 8 KB
  __shared__ float  ldsAhi[2][2048];  // 2 x 8 KB
  __shared__ ushort ldsB[2][4096];    // 2 x 8 KB
  __shared__ float scpart[2][128];    // 1 KB   (total 50176 B -> 3 blocks/CU)

  const int tid = threadIdx.x;
  const int lane = tid & 63;
  const int wid = tid >> 6;           // 0..3
  const int wr = wid >> 1, wc = wid & 1;
  const int m = lane & 15, q = lane >> 4;

  const int bid = blockIdx.x;         // 0..1535
  const int xcd = bid & 7;
  const int slot = bid >> 3;          // 0..191
  const int mtile = xcd * 32 + slot / 6;
  const int ntile = slot % 6;

  const char* const Abase = (const char*)(H + (size_t)(mtile * 128) * 768);
  const char* const Bbase = (const char*)Wt + (size_t)(ntile * 128) * 1536;

  // --- A staging source inverse (LO/HI) ---
  const int tr3 = tid >> 3;                       // 0..31
  const int au = (tid & 7) ^ (tr3 & 7);           // u' = half*4 + v
  const size_t asrcLO = (size_t)((au >> 2) * 64 + tr3) * 3072 + (au & 3) * 32;

  // --- B staging source (f16 packed-pair) ---
  const size_t bsrc0 = (size_t)((au >> 2) * 64 + tr3) * 1536 + (au & 3) * 16;
  const size_t bsrc1 = (size_t)((au >> 2) * 64 + 32 + tr3) * 1536 + (au & 3) * 16;
  const int wavebase = wid << 10;

  f32x4 acc[4][4];
  #pragma unroll
  for (int i = 0; i < 4; ++i)
    #pragma unroll
    for (int j = 0; j < 4; ++j)
      acc[i][j] = (f32x4){0.f, 0.f, 0.f, 0.f};

  auto stage = [&](int kt, int s) {
    #pragma unroll
    for (int c = 0; c < 2; ++c) {
      const char* srcLO = Abase + asrcLO + (size_t)c * 98304 + kt * 128;
      gload_lds16(srcLO,      (char*)ldsAlo[s] + c * 4096 + wavebase);
      gload_lds16(srcLO + 16, (char*)ldsAhi[s] + c * 4096 + wavebase);
    }
    gload_lds16(Bbase + bsrc0 + kt * 64, (char*)ldsB[s] + wavebase);
    gload_lds16(Bbase + bsrc1 + kt * 64, (char*)ldsB[s] + 4096 + wavebase);
  };

  // read-side swizzled byte offsets (measured-0 algebra)
  const int aslot = ((wr * 4 + q) ^ (m & 7)) * 16;  // A: half = wr
  const int bslot = ((wc * 4 + q) ^ (m & 7)) * 16;  // B

  // side-product store base: row = mtile*128 + wr*64 + m (+ mi*16), col q*8
  ushort* const ahbase = Ah + (size_t)(mtile * 128 + wr * 64 + m) * 768 + q * 8;

  auto compute = [&](int s, int t) {
    const char* AbLO = (const char*)ldsAlo[s];
    const char* AbHI = (const char*)ldsAhi[s];
    const char* Bb = (const char*)ldsB[s];
    half8 areg[4], breg[4];
    #pragma unroll
    for (int mi = 0; mi < 4; ++mi) {
      int rowb = (mi * 16 + m) * 128;
      f32x4 lo = *(const f32x4*)(AbLO + rowb + aslot);   // k = 8q..8q+3
      f32x4 hi = *(const f32x4*)(AbHI + rowb + aslot);   // k = 8q+4..8q+7
      half8 r;
      r[0] = (_Float16)lo[0]; r[1] = (_Float16)lo[1];
      r[2] = (_Float16)lo[2]; r[3] = (_Float16)lo[3];
      r[4] = (_Float16)hi[0]; r[5] = (_Float16)hi[1];
      r[6] = (_Float16)hi[2]; r[7] = (_Float16)hi[3];
      areg[mi] = r;
    }
    if ((t % 6) == ntile && wc == 0) {        // f16 side-product (balanced)
      #pragma unroll
      for (int mi = 0; mi < 4; ++mi)
        *(half8*)(ahbase + (size_t)(mi * 16) * 768 + t * 32) = areg[mi];
    }
    #pragma unroll
    for (int ni = 0; ni < 4; ++ni)
      breg[ni] = *(const half8*)(Bb + (ni * 16 + m) * 128 + bslot);
    __builtin_amdgcn_s_setprio(1);
    #pragma unroll
    for (int mi = 0; mi < 4; ++mi)
      #pragma unroll
      for (int ni = 0; ni < 4; ++ni)
        acc[mi][ni] = __builtin_amdgcn_mfma_f32_16x16x32_f16(
            areg[mi], breg[ni], acc[mi][ni], 0, 0, 0);
    __builtin_amdgcn_s_setprio(0);
  };

  // --- dbuf loop: stage(t+1) | compute(t) | sync ---
  stage(0, 0);
  __syncthreads();
  #pragma unroll
  for (int t = 0; t < 24; ++t) {
    if (t < 23) stage(t + 1, (t + 1) & 1);
    compute(t & 1, t);
    __syncthreads();
  }

  // epilogue: score partial = sum_e tanh(acc + b[e]) * c[e]
  float bb[4], cc[4];
  #pragma unroll
  for (int ni = 0; ni < 4; ++ni) {
    int e = ntile * 128 + wc * 64 + ni * 16 + m;
    bb[ni] = bias[e];
    cc[ni] = cvec[e];
  }
  #pragma unroll
  for (int mi = 0; mi < 4; ++mi) {
    #pragma unroll
    for (int j = 0; j < 4; ++j) {
      float s = 0.f;
      #pragma unroll
      for (int ni = 0; ni < 4; ++ni)
        s += tanh_fast(acc[mi][ni][j] + bb[ni]) * cc[ni];
      s += __shfl_xor(s, 1);
      s += __shfl_xor(s, 2);
      s += __shfl_xor(s, 4);
      s += __shfl_xor(s, 8);
      if (m == 0) scpart[wc][wr * 64 + mi * 16 + q * 4 + j] = s;
    }
  }
  __syncthreads();
  if (tid < 128)
    part[ntile * 32768 + mtile * 128 + tid] = scpart[0][tid] + scpart[1][tid];
}

// ---------------- fused softmax + weighted sum (f16 Ah side-product) ----------
__global__ void wsum_fused(const ushort* __restrict__ Ah, const float* __restrict__ prt,
                           float* __restrict__ out) {
  int b = blockIdx.x, dc = blockIdx.y;   // grid (64,3), 128 threads
  int t = threadIdx.x;
  __shared__ float w[512];
  __shared__ float redm[2], reds[2];

  float s[4];
  #pragma unroll
  for (int i = 0; i < 4; ++i) {
    int r = b * 512 + t + i * 128;
    s[i] = prt[r] + prt[32768 + r] + prt[2 * 32768 + r] +
           prt[3 * 32768 + r] + prt[4 * 32768 + r] + prt[5 * 32768 + r];
  }
  float mx = fmaxf(fmaxf(s[0], s[1]), fmaxf(s[2], s[3]));
  #pragma unroll
  for (int o = 32; o >= 1; o >>= 1) mx = fmaxf(mx, __shfl_xor(mx, o));
  if ((t & 63) == 0) redm[t >> 6] = mx;
  __syncthreads();
  mx = fmaxf(redm[0], redm[1]);

  float e[4], sm = 0.f;
  #pragma unroll
  for (int i = 0; i < 4; ++i) { e[i] = __expf(s[i] - mx); sm += e[i]; }
  #pragma unroll
  for (int o = 32; o >= 1; o >>= 1) sm += __shfl_xor(sm, o);
  if ((t & 63) == 0) reds[t >> 6] = sm;
  __syncthreads();
  float inv = 1.0f / (reds[0] + reds[1]);
  #pragma unroll
  for (int i = 0; i < 4; ++i) w[t + i * 128] = e[i] * inv;
  __syncthreads();

  int d0 = dc * 256 + t * 2;
  const ushort* hp = Ah + (size_t)b * 512 * 768 + d0;
  float a0 = 0.f, a1 = 0.f;
  #pragma unroll 8
  for (int l = 0; l < 512; ++l) {
    unsigned u = *(const unsigned*)(hp + (size_t)l * 768);
    float wl = w[l];
    a0 += wl * (float)__builtin_bit_cast(_Float16, (unsigned short)(u & 0xffff));
    a1 += wl * (float)__builtin_bit_cast(_Float16, (unsigned short)(u >> 16));
  }
  out[b * 768 + d0] = a0;
  out[b * 768 + d0 + 1] = a1;

  if (dc == 0) {
    #pragma unroll
    for (int i = 0; i < 4; ++i)
      out[49152 + b * 512 + t + i * 128] = w[t + i * 128];
  }
}

// ---------------- launch ----------------
extern "C" void kernel_launch(void* const* d_in, const int* in_sizes, int n_in,
                              void* d_out, int out_size, void* d_ws, size_t ws_size,
                              hipStream_t stream) {
  const float* H    = (const float*)d_in[0];   // [64,512,768] fp32
  const float* W    = (const float*)d_in[1];   // [768,768]
  const float* bias = (const float*)d_in[2];   // [768]
  const float* cvec = (const float*)d_in[3];   // [768,1]
  float* out = (float*)d_out;                  // [0,49152): weighted ; [49152,81920): attn

  char* ws = (char*)d_ws;
  ushort* Wt = (ushort*)(ws + 0);              //  1,179,648 B
  float*  prt = (float*)(ws + 1179648);        //    786,432 B ([6][32768])
  ushort* Ah = (ushort*)(ws + 1966080);        // 50,331,648 B (f16 side-product)

  hipLaunchKernelGGL(convert_w, dim3(576), dim3(256), 0, stream,
                     (const float4*)W, (ushort4*)Wt);
  hipLaunchKernelGGL(gemm_scores, dim3(1536), dim3(256), 0, stream,
                     H, Wt, bias, cvec, prt, Ah);
  hipLaunchKernelGGL(wsum_fused, dim3(64, 3), dim3(128), 0, stream,
                     Ah, prt, out);
}

// Round 16
// 105.490 us; speedup vs baseline: 1.0024x; 1.0005x over previous
//
#include <hip/hip_runtime.h>
#include <hip/hip_bf16.h>

// CustomAttention: proj = tanh(H @ W^T + b); scores = proj @ c; attn = softmax_L(scores);
// out0 = sum_l H * attn ; out1 = attn.   B=64, L=512, D=768.  M = B*L = 32768.
// FINAL (r13 consolidation, best measured 105.4 us):
//   - no convert_h: GEMM stages fp32 H directly via global_load_lds and converts
//     to f16 in registers post-ds_read (RNE, same numerics as a convert pass).
//   - GEMM: 128x128 tile, BK=32, 4 waves, dbuf single-barrier loop, XCD-affinity
//     block decode (6 same-mtile blocks per XCD -> A rereads L2-local).
//   - wsum: fused softmax + weighted sum reading fp32 H (exact, HBM-bound).
// Session plateau: ten GEMM structural variants (2-phase dbuf, counted-vmcnt
// 8-phase, one-pass BN=768, 256x384 traffic-optimal, 4-block residency, T14
// reg-staging, depth-2 raw-barrier, fp32-direct, f16 side-product) all land at
// 79-87 us timed -- a per-K-step latency floor at this short-K shape, with all
// pipes <35% busy.  Independent counter predictions (occupancy, conflicts,
// FETCH, staged bytes) each verified while duration stayed fixed.

using half8 = __attribute__((ext_vector_type(8))) _Float16;   // MFMA A/B frag (4 VGPRs)
using f32x4 = __attribute__((ext_vector_type(4))) float;      // MFMA C/D frag

#define AS1 __attribute__((address_space(1)))
#define AS3 __attribute__((address_space(3)))

__device__ __forceinline__ void gload_lds16(const void* g, void* l) {
  __builtin_amdgcn_global_load_lds((const AS1 void*)g, (AS3 void*)l, 16, 0, 0);
}

__device__ __forceinline__ unsigned short f2h(float x) {
  _Float16 h = (_Float16)x;                       // v_cvt_f16_f32, RNE
  return __builtin_bit_cast(unsigned short, h);
}

// tanh(x) = 1 - 2/(exp(2x)+1).
__device__ __forceinline__ float tanh_fast(float x) {
  return 1.0f - __fdividef(2.0f, 1.0f + __expf(2.0f * x));
}

// ---------------- W conversion (1.18 MB, ~0.5 us) ----------------
__global__ void convert_w(const float4* __restrict__ W4, ushort4* __restrict__ Wt) {
  int i = blockIdx.x * 256 + threadIdx.x;   // 147456 quads
  float4 x = W4[i];
  ushort4 o;
  o.x = f2h(x.x); o.y = f2h(x.y); o.z = f2h(x.z); o.w = f2h(x.w);
  Wt[i] = o;
}

// ---------------- GEMM (128x128, BK=32, fp32 A direct) + epilogue ----------
__global__ __launch_bounds__(256) void gemm_scores(
    const float* __restrict__ H, const ushort* __restrict__ Wt,
    const float* __restrict__ bias, const float* __restrict__ cvec,
    float* __restrict__ part) {
  __shared__ float  ldsA[2][4096];    // 2 x 16 KB (fp32 A)
  __shared__ ushort ldsB[2][4096];    // 2 x  8 KB (f16 B)
  __shared__ float scpart[2][128];    // 1 KB   (total 50176 B -> 3 blocks/CU)

  const int tid = threadIdx.x;
  const int lane = tid & 63;
  const int wid = tid >> 6;           // 0..3
  const int wr = wid >> 1, wc = wid & 1;
  const int m = lane & 15, q = lane >> 4;

  const int bid = blockIdx.x;         // 0..1535
  const int xcd = bid & 7;
  const int slot = bid >> 3;          // 0..191
  const int mtile = xcd * 32 + slot / 6;
  const int ntile = slot % 6;

  const char* const Abase = (const char*)(H + (size_t)(mtile * 128) * 768);
  const char* const Bbase = (const char*)Wt + (size_t)(ntile * 128) * 1536;

  // --- A staging source (fp32): thread t, chunk c -> r=c*32+tr3, u fixed ---
  const int tr3 = tid >> 3;                       // 0..31
  const int au = (tid & 7) ^ (tr3 & 7);           // unit 0..7 (c-independent)
  const size_t asrc0 = (size_t)tr3 * 3072 + au * 16;   // + c*98304 + kt*128

  // --- B staging source (f16 packed-pair, measured 0 conflicts) ---
  const int up = (tid & 7) ^ (tr3 & 7);
  const size_t bsrc0 = (size_t)((up >> 2) * 64 + tr3) * 1536 + (up & 3) * 16;
  const size_t bsrc1 = (size_t)((up >> 2) * 64 + 32 + tr3) * 1536 + (up & 3) * 16;
  const int wavebase = wid << 10;

  f32x4 acc[4][4];
  #pragma unroll
  for (int i = 0; i < 4; ++i)
    #pragma unroll
    for (int j = 0; j < 4; ++j)
      acc[i][j] = (f32x4){0.f, 0.f, 0.f, 0.f};

  auto stage = [&](int kt, int s) {
    #pragma unroll
    for (int c = 0; c < 4; ++c)
      gload_lds16(Abase + asrc0 + (size_t)c * 98304 + kt * 128,
                  (char*)ldsA[s] + c * 4096 + wavebase);
    gload_lds16(Bbase + bsrc0 + kt * 64, (char*)ldsB[s] + wavebase);
    gload_lds16(Bbase + bsrc1 + kt * 64, (char*)ldsB[s] + 4096 + wavebase);
  };

  // read-side byte offsets
  const int aoff0 = ((2 * q) ^ (m & 7)) * 16;       // A slot c=0; c=1 is ^16
  const int bslot = ((wc * 4 + q) ^ (m & 7)) * 16;  // B (measured-0 algebra)

  auto compute = [&](int s) {
    const char* Ab = (const char*)ldsA[s];
    const char* Bb = (const char*)ldsB[s];
    half8 areg[4], breg[4];
    #pragma unroll
    for (int mi = 0; mi < 4; ++mi) {
      int rowb = (wr * 64 + mi * 16 + m) * 128;
      f32x4 lo = *(const f32x4*)(Ab + rowb + aoff0);
      f32x4 hi = *(const f32x4*)(Ab + rowb + (aoff0 ^ 16));
      half8 r;
      r[0] = (_Float16)lo[0]; r[1] = (_Float16)lo[1];
      r[2] = (_Float16)lo[2]; r[3] = (_Float16)lo[3];
      r[4] = (_Float16)hi[0]; r[5] = (_Float16)hi[1];
      r[6] = (_Float16)hi[2]; r[7] = (_Float16)hi[3];
      areg[mi] = r;
    }
    #pragma unroll
    for (int ni = 0; ni < 4; ++ni)
      breg[ni] = *(const half8*)(Bb + (ni * 16 + m) * 128 + bslot);
    __builtin_amdgcn_s_setprio(1);
    #pragma unroll
    for (int mi = 0; mi < 4; ++mi)
      #pragma unroll
      for (int ni = 0; ni < 4; ++ni)
        acc[mi][ni] = __builtin_amdgcn_mfma_f32_16x16x32_f16(
            areg[mi], breg[ni], acc[mi][ni], 0, 0, 0);
    __builtin_amdgcn_s_setprio(0);
  };

  // --- dbuf loop: stage(t+1) | compute(t) | sync ---
  stage(0, 0);
  __syncthreads();
  #pragma unroll
  for (int t = 0; t < 24; ++t) {
    if (t < 23) stage(t + 1, (t + 1) & 1);
    compute(t & 1);
    __syncthreads();
  }

  // epilogue: score partial = sum_e tanh(acc + b[e]) * c[e]
  float bb[4], cc[4];
  #pragma unroll
  for (int ni = 0; ni < 4; ++ni) {
    int e = ntile * 128 + wc * 64 + ni * 16 + m;
    bb[ni] = bias[e];
    cc[ni] = cvec[e];
  }
  #pragma unroll
  for (int mi = 0; mi < 4; ++mi) {
    #pragma unroll
    for (int j = 0; j < 4; ++j) {
      float s = 0.f;
      #pragma unroll
      for (int ni = 0; ni < 4; ++ni)
        s += tanh_fast(acc[mi][ni][j] + bb[ni]) * cc[ni];
      s += __shfl_xor(s, 1);
      s += __shfl_xor(s, 2);
      s += __shfl_xor(s, 4);
      s += __shfl_xor(s, 8);
      if (m == 0) scpart[wc][wr * 64 + mi * 16 + q * 4 + j] = s;
    }
  }
  __syncthreads();
  if (tid < 128)
    part[ntile * 32768 + mtile * 128 + tid] = scpart[0][tid] + scpart[1][tid];
}

// ---------------- fused softmax + weighted sum (fp32 H, exact) ----------------
__global__ void wsum_fused(const float* __restrict__ H, const float* __restrict__ prt,
                           float* __restrict__ out) {
  int b = blockIdx.x, dc = blockIdx.y;   // grid (64,3), 128 threads
  int t = threadIdx.x;
  __shared__ float w[512];
  __shared__ float redm[2], reds[2];

  float s[4];
  #pragma unroll
  for (int i = 0; i < 4; ++i) {
    int r = b * 512 + t + i * 128;
    s[i] = prt[r] + prt[32768 + r] + prt[2 * 32768 + r] +
           prt[3 * 32768 + r] + prt[4 * 32768 + r] + prt[5 * 32768 + r];
  }
  float mx = fmaxf(fmaxf(s[0], s[1]), fmaxf(s[2], s[3]));
  #pragma unroll
  for (int o = 32; o >= 1; o >>= 1) mx = fmaxf(mx, __shfl_xor(mx, o));
  if ((t & 63) == 0) redm[t >> 6] = mx;
  __syncthreads();
  mx = fmaxf(redm[0], redm[1]);

  float e[4], sm = 0.f;
  #pragma unroll
  for (int i = 0; i < 4; ++i) { e[i] = __expf(s[i] - mx); sm += e[i]; }
  #pragma unroll
  for (int o = 32; o >= 1; o >>= 1) sm += __shfl_xor(sm, o);
  if ((t & 63) == 0) reds[t >> 6] = sm;
  __syncthreads();
  float inv = 1.0f / (reds[0] + reds[1]);
  #pragma unroll
  for (int i = 0; i < 4; ++i) w[t + i * 128] = e[i] * inv;
  __syncthreads();

  int d0 = dc * 256 + t * 2;
  const float2* hp = (const float2*)(H + (size_t)b * 512 * 768 + d0);
  float a0 = 0.f, a1 = 0.f;
  #pragma unroll 8
  for (int l = 0; l < 512; ++l) {
    float2 u = hp[(size_t)l * 384];
    float wl = w[l];
    a0 += wl * u.x;
    a1 += wl * u.y;
  }
  out[b * 768 + d0] = a0;
  out[b * 768 + d0 + 1] = a1;

  if (dc == 0) {
    #pragma unroll
    for (int i = 0; i < 4; ++i)
      out[49152 + b * 512 + t + i * 128] = w[t + i * 128];
  }
}

// ---------------- launch ----------------
extern "C" void kernel_launch(void* const* d_in, const int* in_sizes, int n_in,
                              void* d_out, int out_size, void* d_ws, size_t ws_size,
                              hipStream_t stream) {
  const float* H    = (const float*)d_in[0];   // [64,512,768] fp32
  const float* W    = (const float*)d_in[1];   // [768,768]
  const float* bias = (const float*)d_in[2];   // [768]
  const float* cvec = (const float*)d_in[3];   // [768,1]
  float* out = (float*)d_out;                  // [0,49152): weighted ; [49152,81920): attn

  char* ws = (char*)d_ws;
  ushort* Wt = (ushort*)(ws + 0);              // 1,179,648 B
  float*  prt = (float*)(ws + 1179648);        //   786,432 B ([6][32768])

  hipLaunchKernelGGL(convert_w, dim3(576), dim3(256), 0, stream,
                     (const float4*)W, (ushort4*)Wt);
  hipLaunchKernelGGL(gemm_scores, dim3(1536), dim3(256), 0, stream,
                     H, Wt, bias, cvec, prt);
  hipLaunchKernelGGL(wsum_fused, dim3(64, 3), dim3(128), 0, stream,
                     H, prt, out);
}